// Round 5
// baseline (7167.987 us; speedup 1.0000x reference)
//
#include <hip/hip_runtime.h>
#include <cstdint>

#define B_SZ 64
#define T_SZ 2048
#define F_SZ 256
#define H_SZ 512

typedef _Float16 f16x8 __attribute__((ext_vector_type(8)));
typedef float f32x4 __attribute__((ext_vector_type(4)));

#if defined(__has_builtin)
#if __has_builtin(__builtin_amdgcn_fdot2)
#define HAVE_FDOT2 1
#endif
#endif
#ifndef HAVE_FDOT2
#define HAVE_FDOT2 0
#endif

typedef _Float16 half2v __attribute__((ext_vector_type(2)));
union H2U { uint32_t u; half2v h; _Float16 e[2]; };

__device__ __forceinline__ float fdot2f(uint32_t a, uint32_t b, float c) {
  H2U ua, ub; ua.u = a; ub.u = b;
#if HAVE_FDOT2
  return __builtin_amdgcn_fdot2(ua.h, ub.h, c, false);
#else
  return c + (float)ua.e[0] * (float)ub.e[0] + (float)ua.e[1] * (float)ub.e[1];
#endif
}

__device__ __forceinline__ uint32_t pack2h(float x, float y) {
  H2U v; v.e[0] = (_Float16)x; v.e[1] = (_Float16)y; return v.u;
}

__device__ __forceinline__ float fast_tanh(float x) {
  float xc = fminf(9.0f, fmaxf(-9.0f, x));
  float e = __expf(2.0f * xc);
  return (e - 1.0f) / (e + 1.0f);
}

// Raw barrier: drain LDS only (h-exchange visibility); global loads/stores
// keep floating across the barrier (counted waits appear at their uses,
// one full step downstream). sched_barrier(0) fences per methodology #18.
__device__ __forceinline__ void step_barrier() {
  __builtin_amdgcn_sched_barrier(0);
  asm volatile("s_waitcnt lgkmcnt(0)\n\ts_barrier" ::: "memory");
  __builtin_amdgcn_sched_barrier(0);
}

// ---------------------------------------------------------------------------
// Kernel 1: xp[m,n] = q·W_ih^T + b_ih + b_hh   (unchanged — ~260 us)
// ---------------------------------------------------------------------------
__global__ __launch_bounds__(256) void proj_kernel(
    const float* __restrict__ q, const float* __restrict__ w_ih,
    const float* __restrict__ b_ih, const float* __restrict__ b_hh,
    float* __restrict__ xp) {
  __shared__ uint32_t lds_a[16][128 + 4];
  __shared__ uint32_t lds_b[16][128 + 4];
  const int tid = threadIdx.x;
  const int nt = blockIdx.x & 3;
  const int mt = blockIdx.x >> 2;
  const int m0 = mt * 128, n0 = nt * 128;
  const int tx = tid & 15, ty = tid >> 4;
  const int sr = tid >> 3, sc4 = tid & 7;

  float bias[8];
#pragma unroll
  for (int j = 0; j < 8; ++j) {
    int n = n0 + tx * 8 + j;
    bias[j] = b_ih[n] + b_hh[n];
  }
  float acc[8][8];
#pragma unroll
  for (int i = 0; i < 8; ++i)
#pragma unroll
    for (int j = 0; j < 8; ++j) acc[i][j] = 0.f;

  for (int k0 = 0; k0 < F_SZ; k0 += 32) {
#pragma unroll
    for (int i = 0; i < 4; ++i) {
      int r = sr + 32 * i;
      float4 v = *(const float4*)(q + (size_t)(m0 + r) * F_SZ + k0 + sc4 * 4);
      lds_a[sc4 * 2 + 0][r] = pack2h(v.x, v.y);
      lds_a[sc4 * 2 + 1][r] = pack2h(v.z, v.w);
      float4 w = *(const float4*)(w_ih + (size_t)(n0 + r) * F_SZ + k0 + sc4 * 4);
      lds_b[sc4 * 2 + 0][r] = pack2h(w.x, w.y);
      lds_b[sc4 * 2 + 1][r] = pack2h(w.z, w.w);
    }
    __syncthreads();
#pragma unroll
    for (int kp = 0; kp < 16; ++kp) {
      uint32_t a8[8], b8[8];
#pragma unroll
      for (int i = 0; i < 8; ++i) a8[i] = lds_a[kp][ty * 8 + i];
#pragma unroll
      for (int j = 0; j < 8; ++j) b8[j] = lds_b[kp][tx * 8 + j];
#pragma unroll
      for (int i = 0; i < 8; ++i)
#pragma unroll
        for (int j = 0; j < 8; ++j)
          acc[i][j] = fdot2f(a8[i], b8[j], acc[i][j]);
    }
    __syncthreads();
  }
#pragma unroll
  for (int i = 0; i < 8; ++i) {
    size_t row = (size_t)(m0 + ty * 8 + i);
    float4 o0, o1;
    o0.x = acc[i][0] + bias[0]; o0.y = acc[i][1] + bias[1];
    o0.z = acc[i][2] + bias[2]; o0.w = acc[i][3] + bias[3];
    o1.x = acc[i][4] + bias[4]; o1.y = acc[i][5] + bias[5];
    o1.z = acc[i][6] + bias[6]; o1.w = acc[i][7] + bias[7];
    *(float4*)(xp + row * H_SZ + n0 + tx * 8) = o0;
    *(float4*)(xp + row * H_SZ + n0 + tx * 8 + 4) = o1;
  }
}

// ---------------------------------------------------------------------------
// Kernel 2: recurrence via MFMA, W_hh fully register-resident (256 regs/
// thread of A-fragments). One 512-thread WG (8 waves) per batch row; wave w
// owns rows 64w..64w+63 as 4 row-tiles x 16 k-tiles of mfma_f32_16x16x32_f16.
// Per step: 16 broadcast b128 h-reads, 64 MFMAs in 8 independent chains
// (even/odd kt), uniform 16->1 select epilogue, one RAW s_barrier with
// lgkmcnt-only drain (global xp-load / h-store float across steps).
// C/D layout (HW-verified): col=lane&15, row=(lane>>4)*4+reg.
// ---------------------------------------------------------------------------
__global__ __attribute__((amdgpu_flat_work_group_size(512, 512),
                          amdgpu_waves_per_eu(2, 2)))
void rnn_kernel(const float* __restrict__ w_hh, float* __restrict__ out) {
  extern __shared__ char smem[];
  _Float16* lds_h = (_Float16*)smem;  // 2 x 512 halves (rest of LDS = pad)

  const int b = blockIdx.x;
  const int tid = threadIdx.x;
  const int w = tid >> 6;
  const int lane = tid & 63;
  const int m = lane & 15;   // A row within tile / C col
  const int g = lane >> 4;   // k-group / C row-group

  // --- A-fragments: af[tile][kt] covers row 64w+tile*16+m, k=kt*32+g*8+i ---
  f16x8 af[4][16];
#pragma unroll
  for (int tile = 0; tile < 4; ++tile) {
    const float* rowp = w_hh + (size_t)(64 * w + tile * 16 + m) * H_SZ;
#pragma unroll
    for (int kt = 0; kt < 16; ++kt) {
      const float* p = rowp + kt * 32 + g * 8;
      float4 v0 = *(const float4*)p;
      float4 v1 = *(const float4*)(p + 4);
      f16x8 a;
      a[0] = (_Float16)v0.x; a[1] = (_Float16)v0.y;
      a[2] = (_Float16)v0.z; a[3] = (_Float16)v0.w;
      a[4] = (_Float16)v1.x; a[5] = (_Float16)v1.y;
      a[6] = (_Float16)v1.z; a[7] = (_Float16)v1.w;
      af[tile][kt] = a;
    }
  }
  // h0 = 0, both buffers
  lds_h[tid] = (_Float16)0.f;
  lds_h[512 + tid] = (_Float16)0.f;
  __syncthreads();  // one-time full barrier (drains W loads too) — fine

  // this lane's output row (bijective within the block)
  const int row = 64 * w + (m >> 2) * 16 + g * 4 + (m & 3);
  const bool b8 = (m & 8) != 0, b4 = (m & 4) != 0;
  const bool b2 = (m & 2) != 0, b1 = (m & 1) != 0;

  float* outb = out + (size_t)b * T_SZ * H_SZ;
  float xc = outb[row];  // xp for t=0
  float hlast = 0.f;

#pragma unroll 1
  for (int t = 0; t < T_SZ; ++t) {
    // prefetch next xp; with the raw barrier this load floats a full step
    int tn = (t + 1 < T_SZ) ? t + 1 : t;
    float xn = outb[(size_t)tn * H_SZ + row];

    const _Float16* hb = lds_h + (t & 1) * 512;
    // 8 independent accumulator chains (even/odd kt), depth 8 each
    f32x4 c0a = {0.f, 0.f, 0.f, 0.f}, c1a = c0a, c2a = c0a, c3a = c0a;
    f32x4 c0b = c0a, c1b = c0a, c2b = c0a, c3b = c0a;
#pragma unroll
    for (int kp = 0; kp < 8; ++kp) {
      f16x8 bfe = *(const f16x8*)(hb + (2 * kp) * 32 + g * 8);
      f16x8 bfo = *(const f16x8*)(hb + (2 * kp + 1) * 32 + g * 8);
      c0a = __builtin_amdgcn_mfma_f32_16x16x32_f16(af[0][2 * kp], bfe, c0a, 0, 0, 0);
      c1a = __builtin_amdgcn_mfma_f32_16x16x32_f16(af[1][2 * kp], bfe, c1a, 0, 0, 0);
      c2a = __builtin_amdgcn_mfma_f32_16x16x32_f16(af[2][2 * kp], bfe, c2a, 0, 0, 0);
      c3a = __builtin_amdgcn_mfma_f32_16x16x32_f16(af[3][2 * kp], bfe, c3a, 0, 0, 0);
      c0b = __builtin_amdgcn_mfma_f32_16x16x32_f16(af[0][2 * kp + 1], bfo, c0b, 0, 0, 0);
      c1b = __builtin_amdgcn_mfma_f32_16x16x32_f16(af[1][2 * kp + 1], bfo, c1b, 0, 0, 0);
      c2b = __builtin_amdgcn_mfma_f32_16x16x32_f16(af[2][2 * kp + 1], bfo, c2b, 0, 0, 0);
      c3b = __builtin_amdgcn_mfma_f32_16x16x32_f16(af[3][2 * kp + 1], bfo, c3b, 0, 0, 0);
    }
    f32x4 s0 = c0a + c0b, s1 = c1a + c1b, s2 = c2a + c2b, s3 = c3a + c3b;

    // static 16->1 select: tile = m>>2 (bits b8,b4), reg = m&3 (bits b2,b1)
    float p0 = b8 ? (b4 ? s3[0] : s2[0]) : (b4 ? s1[0] : s0[0]);
    float p1 = b8 ? (b4 ? s3[1] : s2[1]) : (b4 ? s1[1] : s0[1]);
    float p2 = b8 ? (b4 ? s3[2] : s2[2]) : (b4 ? s1[2] : s0[2]);
    float p3 = b8 ? (b4 ? s3[3] : s2[3]) : (b4 ? s1[3] : s0[3]);
    float q01 = b1 ? p1 : p0;
    float q23 = b1 ? p3 : p2;
    float v = b2 ? q23 : q01;

    float hnew = fast_tanh(xc + v);
    outb[(size_t)t * H_SZ + row] = hnew;                 // floats past barrier
    lds_h[((t + 1) & 1) * 512 + row] = (_Float16)hnew;   // drained by barrier
    hlast = hnew;
    xc = xn;
    step_barrier();
  }

  // hidden = h_{T-1}
  out[(size_t)B_SZ * T_SZ * H_SZ + (size_t)b * H_SZ + row] = hlast;
}

extern "C" void kernel_launch(void* const* d_in, const int* in_sizes, int n_in,
                              void* d_out, int out_size, void* d_ws,
                              size_t ws_size, hipStream_t stream) {
  (void)in_sizes; (void)n_in; (void)out_size; (void)d_ws; (void)ws_size;
  const float* q    = (const float*)d_in[0];
  const float* w_ih = (const float*)d_in[1];
  const float* w_hh = (const float*)d_in[2];
  const float* b_ih = (const float*)d_in[3];
  const float* b_hh = (const float*)d_in[4];
  float* out = (float*)d_out;

  proj_kernel<<<dim3((B_SZ * T_SZ / 128) * (H_SZ / 128)), dim3(256), 0,
                stream>>>(q, w_ih, b_ih, b_hh, out);

  // Only 2 KB used, but request 96 KB to pin exactly 1 WG per CU.
  hipFuncSetAttribute(reinterpret_cast<const void*>(rnn_kernel),
                      hipFuncAttributeMaxDynamicSharedMemorySize, 98304);
  rnn_kernel<<<dim3(B_SZ), dim3(512), 98304, stream>>>(w_hh, out);
}

// Round 6
// 3386.887 us; speedup vs baseline: 2.1164x; 2.1164x over previous
//
#include <hip/hip_runtime.h>
#include <cstdint>

#define B_SZ 64
#define T_SZ 2048
#define F_SZ 256
#define H_SZ 512

typedef _Float16 f16x8 __attribute__((ext_vector_type(8)));
typedef float f32x4 __attribute__((ext_vector_type(4)));

#if defined(__has_builtin)
#if __has_builtin(__builtin_amdgcn_fdot2)
#define HAVE_FDOT2 1
#endif
#endif
#ifndef HAVE_FDOT2
#define HAVE_FDOT2 0
#endif

typedef _Float16 half2v __attribute__((ext_vector_type(2)));
union H2U { uint32_t u; half2v h; _Float16 e[2]; };

__device__ __forceinline__ float fdot2f(uint32_t a, uint32_t b, float c) {
  H2U ua, ub; ua.u = a; ub.u = b;
#if HAVE_FDOT2
  return __builtin_amdgcn_fdot2(ua.h, ub.h, c, false);
#else
  return c + (float)ua.e[0] * (float)ub.e[0] + (float)ua.e[1] * (float)ub.e[1];
#endif
}

__device__ __forceinline__ uint32_t pack2h(float x, float y) {
  H2U v; v.e[0] = (_Float16)x; v.e[1] = (_Float16)y; return v.u;
}

__device__ __forceinline__ float fast_tanh(float x) {
  float xc = fminf(9.0f, fmaxf(-9.0f, x));
  float e = __expf(2.0f * xc);
  return (e - 1.0f) / (e + 1.0f);
}

__device__ __forceinline__ f16x8 pack8(const float* p) {
  float4 v0 = *(const float4*)p;
  float4 v1 = *(const float4*)(p + 4);
  f16x8 a;
  a[0] = (_Float16)v0.x; a[1] = (_Float16)v0.y;
  a[2] = (_Float16)v0.z; a[3] = (_Float16)v0.w;
  a[4] = (_Float16)v1.x; a[5] = (_Float16)v1.y;
  a[6] = (_Float16)v1.z; a[7] = (_Float16)v1.w;
  return a;
}

// Raw per-step barrier: drain LDS ops only (h-exchange visibility). Global
// xp-loads / h-stores / streamed-W loads float across it with counted waits
// at their uses. "memory" clobber orders all memory ops vs the barrier.
__device__ __forceinline__ void step_barrier() {
  asm volatile("s_waitcnt lgkmcnt(0)\n\ts_barrier" ::: "memory");
}

// ---------------------------------------------------------------------------
// Kernel 0: pre-pack the streamed quarter of W_hh (rows 64w+48..63 per wave)
// into fp16 MFMA A-fragments, fragment-linear in d_ws:
//   wsf[(w*16 + kt)*64 + lane] = frag(row 64*w+48+(lane&15), k=kt*32+(lane>>4)*8)
// ---------------------------------------------------------------------------
__global__ __launch_bounds__(512) void prep_kernel(
    const float* __restrict__ w_hh, uint4* __restrict__ wsf) {
  int idx = blockIdx.x * 512 + threadIdx.x;   // 0..8191
  int lane = idx & 63;
  int kt = (idx >> 6) & 15;
  int w = idx >> 10;
  int m = lane & 15, g = lane >> 4;
  const float* p = w_hh + (size_t)(64 * w + 48 + m) * H_SZ + kt * 32 + g * 8;
  f16x8 a = pack8(p);
  wsf[idx] = __builtin_bit_cast(uint4, a);
}

// ---------------------------------------------------------------------------
// Kernel 1: xp[m,n] = q·W_ih^T + b_ih + b_hh   (unchanged — ~290 us)
// ---------------------------------------------------------------------------
__global__ __launch_bounds__(256) void proj_kernel(
    const float* __restrict__ q, const float* __restrict__ w_ih,
    const float* __restrict__ b_ih, const float* __restrict__ b_hh,
    float* __restrict__ xp) {
  __shared__ uint32_t lds_a[16][128 + 4];
  __shared__ uint32_t lds_b[16][128 + 4];
  const int tid = threadIdx.x;
  const int nt = blockIdx.x & 3;
  const int mt = blockIdx.x >> 2;
  const int m0 = mt * 128, n0 = nt * 128;
  const int tx = tid & 15, ty = tid >> 4;
  const int sr = tid >> 3, sc4 = tid & 7;

  float bias[8];
#pragma unroll
  for (int j = 0; j < 8; ++j) {
    int n = n0 + tx * 8 + j;
    bias[j] = b_ih[n] + b_hh[n];
  }
  float acc[8][8];
#pragma unroll
  for (int i = 0; i < 8; ++i)
#pragma unroll
    for (int j = 0; j < 8; ++j) acc[i][j] = 0.f;

  for (int k0 = 0; k0 < F_SZ; k0 += 32) {
#pragma unroll
    for (int i = 0; i < 4; ++i) {
      int r = sr + 32 * i;
      float4 v = *(const float4*)(q + (size_t)(m0 + r) * F_SZ + k0 + sc4 * 4);
      lds_a[sc4 * 2 + 0][r] = pack2h(v.x, v.y);
      lds_a[sc4 * 2 + 1][r] = pack2h(v.z, v.w);
      float4 w = *(const float4*)(w_ih + (size_t)(n0 + r) * F_SZ + k0 + sc4 * 4);
      lds_b[sc4 * 2 + 0][r] = pack2h(w.x, w.y);
      lds_b[sc4 * 2 + 1][r] = pack2h(w.z, w.w);
    }
    __syncthreads();
#pragma unroll
    for (int kp = 0; kp < 16; ++kp) {
      uint32_t a8[8], b8[8];
#pragma unroll
      for (int i = 0; i < 8; ++i) a8[i] = lds_a[kp][ty * 8 + i];
#pragma unroll
      for (int j = 0; j < 8; ++j) b8[j] = lds_b[kp][tx * 8 + j];
#pragma unroll
      for (int i = 0; i < 8; ++i)
#pragma unroll
        for (int j = 0; j < 8; ++j)
          acc[i][j] = fdot2f(a8[i], b8[j], acc[i][j]);
    }
    __syncthreads();
  }
#pragma unroll
  for (int i = 0; i < 8; ++i) {
    size_t row = (size_t)(m0 + ty * 8 + i);
    float4 o0, o1;
    o0.x = acc[i][0] + bias[0]; o0.y = acc[i][1] + bias[1];
    o0.z = acc[i][2] + bias[2]; o0.w = acc[i][3] + bias[3];
    o1.x = acc[i][4] + bias[4]; o1.y = acc[i][5] + bias[5];
    o1.z = acc[i][6] + bias[6]; o1.w = acc[i][7] + bias[7];
    *(float4*)(xp + row * H_SZ + n0 + tx * 8) = o0;
    *(float4*)(xp + row * H_SZ + n0 + tx * 8 + 4) = o1;
  }
}

// ---------------------------------------------------------------------------
// Kernel 2: recurrence via MFMA. One 512-thread WG (8 waves) per batch row.
// Wave w owns rows 64w..64w+63 as 4 row-tiles of mfma_f32_16x16x32_f16:
//   tiles 0,1: AGPR-resident (af[2][16] = 128 regs; + ~110 arch VGPR fits the
//              256-reg/wave cap at waves_per_eu(2,2) — NO spill this time)
//   tile  2:   LDS-resident (8 x 16 KB, lane-linear, conflict-free b128)
//   tile  3:   streamed from L2 each step (prepacked fp16 frags in d_ws;
//              same addresses every step -> L2-hot; 16 b128 loads issued at
//              step top, consumed at the tail of the kt loop)
// h: fp16[2][512] dbuf in LDS; B-frags are 16-way broadcast b128 reads.
// All 16 MFMA columns equal -> uniform 16->1 static select epilogue.
// Per-step raw barrier drains lgkmcnt only; global ops float across steps.
// ---------------------------------------------------------------------------
__global__ __attribute__((amdgpu_flat_work_group_size(512, 512),
                          amdgpu_waves_per_eu(2, 2)))
void rnn_kernel(const float* __restrict__ w_hh, const uint4* __restrict__ wsf,
                float* __restrict__ out) {
  extern __shared__ char smem[];
  uint4* lds_w = (uint4*)smem;                    // [8][16][64] frags (128 KB)
  _Float16* lds_h = (_Float16*)(smem + 131072);   // 2 x 512

  const int b = blockIdx.x;
  const int tid = threadIdx.x;
  const int w = tid >> 6;
  const int lane = tid & 63;
  const int m = lane & 15;   // A row within tile / C col
  const int g = lane >> 4;   // k-group / C row-group

  // --- AGPR tiles 0,1: rows 64w + tile*16 + m ---
  f16x8 af[2][16];
#pragma unroll
  for (int tile = 0; tile < 2; ++tile) {
    const float* rowp = w_hh + (size_t)(64 * w + tile * 16 + m) * H_SZ;
#pragma unroll
    for (int kt = 0; kt < 16; ++kt)
      af[tile][kt] = pack8(rowp + kt * 32 + g * 8);
  }
  // --- LDS tile 2: rows 64w + 32 + m; each lane writes its own fragment ---
  {
    const float* rowp = w_hh + (size_t)(64 * w + 32 + m) * H_SZ;
#pragma unroll
    for (int kt = 0; kt < 16; ++kt) {
      f16x8 a = pack8(rowp + kt * 32 + g * 8);
      lds_w[(w * 16 + kt) * 64 + lane] = __builtin_bit_cast(uint4, a);
    }
  }
  // h0 = 0, both buffers
  lds_h[tid] = (_Float16)0.f;
  lds_h[512 + tid] = (_Float16)0.f;
  __syncthreads();

  // this lane's output row (bijective within the block)
  const int row = 64 * w + (m >> 2) * 16 + g * 4 + (m & 3);
  const bool b8 = (m & 8) != 0, b4 = (m & 4) != 0;
  const bool b2 = (m & 2) != 0, b1 = (m & 1) != 0;

  const uint4* swp = wsf + (size_t)(w * 16) * 64 + lane;    // stream frags
  const uint4* lwp = lds_w + (w * 16) * 64 + lane;          // LDS frags

  float* outb = out + (size_t)b * T_SZ * H_SZ;
  float xc = outb[row];  // xp for t=0
  float hlast = 0.f;

#pragma unroll 1
  for (int t = 0; t < T_SZ; ++t) {
    // prefetch next xp (floats across the raw barrier, waited one step later)
    int tn = (t + 1 < T_SZ) ? t + 1 : t;
    float xn = outb[(size_t)tn * H_SZ + row];

    // issue all 16 streamed-tile fragment loads up front (L2-hot)
    uint4 sf0 = swp[0 * 64],  sf1 = swp[1 * 64],  sf2 = swp[2 * 64],
          sf3 = swp[3 * 64],  sf4 = swp[4 * 64],  sf5 = swp[5 * 64],
          sf6 = swp[6 * 64],  sf7 = swp[7 * 64],  sf8 = swp[8 * 64],
          sf9 = swp[9 * 64],  sf10 = swp[10 * 64], sf11 = swp[11 * 64],
          sf12 = swp[12 * 64], sf13 = swp[13 * 64], sf14 = swp[14 * 64],
          sf15 = swp[15 * 64];

    const _Float16* hb = lds_h + (t & 1) * 512;
    f32x4 c0 = {0.f, 0.f, 0.f, 0.f}, c1 = c0, c2 = c0, c3 = c0;
#define STEP_KT(kt, sfk)                                                      \
    {                                                                         \
      f16x8 bf = *(const f16x8*)(hb + (kt) * 32 + g * 8);                     \
      c0 = __builtin_amdgcn_mfma_f32_16x16x32_f16(af[0][kt], bf, c0, 0, 0, 0);\
      c1 = __builtin_amdgcn_mfma_f32_16x16x32_f16(af[1][kt], bf, c1, 0, 0, 0);\
      uint4 lf = lwp[(kt) * 64];                                              \
      c2 = __builtin_amdgcn_mfma_f32_16x16x32_f16(                            \
          __builtin_bit_cast(f16x8, lf), bf, c2, 0, 0, 0);                    \
      c3 = __builtin_amdgcn_mfma_f32_16x16x32_f16(                            \
          __builtin_bit_cast(f16x8, sfk), bf, c3, 0, 0, 0);                   \
    }
    STEP_KT(0, sf0)   STEP_KT(1, sf1)   STEP_KT(2, sf2)   STEP_KT(3, sf3)
    STEP_KT(4, sf4)   STEP_KT(5, sf5)   STEP_KT(6, sf6)   STEP_KT(7, sf7)
    STEP_KT(8, sf8)   STEP_KT(9, sf9)   STEP_KT(10, sf10) STEP_KT(11, sf11)
    STEP_KT(12, sf12) STEP_KT(13, sf13) STEP_KT(14, sf14) STEP_KT(15, sf15)
#undef STEP_KT

    // static 16->1 select: tile = m>>2 (bits b8,b4), reg = m&3 (bits b2,b1)
    float p0 = b8 ? (b4 ? c3[0] : c2[0]) : (b4 ? c1[0] : c0[0]);
    float p1 = b8 ? (b4 ? c3[1] : c2[1]) : (b4 ? c1[1] : c0[1]);
    float p2 = b8 ? (b4 ? c3[2] : c2[2]) : (b4 ? c1[2] : c0[2]);
    float p3 = b8 ? (b4 ? c3[3] : c2[3]) : (b4 ? c1[3] : c0[3]);
    float q01 = b1 ? p1 : p0;
    float q23 = b1 ? p3 : p2;
    float v = b2 ? q23 : q01;

    float hnew = fast_tanh(xc + v);
    outb[(size_t)t * H_SZ + row] = hnew;                 // floats past barrier
    lds_h[((t + 1) & 1) * 512 + row] = (_Float16)hnew;   // drained by barrier
    hlast = hnew;
    xc = xn;
    step_barrier();
  }

  // hidden = h_{T-1}
  out[(size_t)B_SZ * T_SZ * H_SZ + (size_t)b * H_SZ + row] = hlast;
}

extern "C" void kernel_launch(void* const* d_in, const int* in_sizes, int n_in,
                              void* d_out, int out_size, void* d_ws,
                              size_t ws_size, hipStream_t stream) {
  (void)in_sizes; (void)n_in; (void)out_size; (void)ws_size;
  const float* q    = (const float*)d_in[0];
  const float* w_ih = (const float*)d_in[1];
  const float* w_hh = (const float*)d_in[2];
  const float* b_ih = (const float*)d_in[3];
  const float* b_hh = (const float*)d_in[4];
  float* out = (float*)d_out;
  uint4* wsf = (uint4*)d_ws;   // 8192 frags x 16 B = 128 KB of scratch

  prep_kernel<<<dim3(16), dim3(512), 0, stream>>>(w_hh, wsf);

  proj_kernel<<<dim3((B_SZ * T_SZ / 128) * (H_SZ / 128)), dim3(256), 0,
                stream>>>(q, w_ih, b_ih, b_hh, out);

  // 131072 (LDS W tiles) + 2048 (h dbuf) = 133120 B dynamic LDS (>64 KB opt-in)
  hipFuncSetAttribute(reinterpret_cast<const void*>(rnn_kernel),
                      hipFuncAttributeMaxDynamicSharedMemorySize, 133120);
  rnn_kernel<<<dim3(B_SZ), dim3(512), 133120, stream>>>(w_hh, wsf, out);
}